// Round 6
// baseline (9947.452 us; speedup 1.0000x reference)
//
#include <hip/hip_runtime.h>
#include <math.h>

// Problem constants (match reference)
#define B_    64
#define T_    2048
#define DIN   256
#define DH    256
#define DC    256
#define DOUT  256
#define K2    512   // DIN + DH
#define SPAIR 12    // k-pairs per slice stashed in LDS (of 32)

typedef _Float16 half2_t __attribute__((ext_vector_type(2)));

#if defined(__has_builtin)
#  if __has_builtin(__builtin_amdgcn_fdot2)
#    define FDOT2(a,b,c) __builtin_amdgcn_fdot2((a),(b),(c),false)
#  endif
#endif
#ifndef FDOT2   // scalar fallback if builtin unavailable
#  define FDOT2(a,b,c) ((c) + (float)(a)[0]*(float)(b)[0] + (float)(a)[1]*(float)(b)[1])
#endif

__device__ __forceinline__ float sigmoidf_(float x) {
    return 1.0f / (1.0f + __expf(-x));
}

__device__ __forceinline__ float tanhf_(float x) {
    float ax = fabsf(x);
    float e  = __expf(-2.0f * ax);
    float t  = (1.0f - e) / (1.0f + e);
    return copysignf(t, x);
}

// ---------------------------------------------------------------------------
// Phase 0: pack h-half gate weights to fp16 k-pairs.
// Wp[g][k2][n] = ( W[256+2k2][n], W[256+2k2+1][n] ) as half2. 393 KB total.
// ---------------------------------------------------------------------------
__global__ __launch_bounds__(256) void packw(
    const float* __restrict__ Wf, const float* __restrict__ Wi,
    const float* __restrict__ Wo, half2_t* __restrict__ Wp)
{
    const int g     = blockIdx.x;        // gate 0..2
    const int chunk = blockIdx.y;        // 16 chunks x 8 k-pairs
    const int n     = threadIdx.x;
    const float* W = ((g == 0) ? Wf : (g == 1) ? Wi : Wo) + (size_t)DIN * DC;
    #pragma unroll
    for (int j = 0; j < 8; ++j) {
        const int k2 = chunk * 8 + j;
        half2_t p;
        p[0] = (_Float16)W[(size_t)(2 * k2)     * DC + n];
        p[1] = (_Float16)W[(size_t)(2 * k2 + 1) * DC + n];
        Wp[((size_t)g * 128 + k2) * 256 + n] = p;
    }
}

// ---------------------------------------------------------------------------
// Phase 1: P[b,t,g*256+n] = x[b,t,:] @ Wg[0:256,:] + bg   (no recurrence)
// ---------------------------------------------------------------------------
__global__ __launch_bounds__(256) void xgemm(
    const float* __restrict__ x,
    const float* __restrict__ Wf, const float* __restrict__ bf,
    const float* __restrict__ Wi, const float* __restrict__ bi,
    const float* __restrict__ Wo, const float* __restrict__ bo,
    float* __restrict__ P)
{
    const int mt  = blockIdx.x;
    const int g   = blockIdx.y;
    const float* W    = (g == 0) ? Wf : (g == 1) ? Wi : Wo;
    const float* bias = (g == 0) ? bf : (g == 1) ? bi : bo;
    const int tid  = threadIdx.x;
    const int lane = tid & 63;
    const int rg   = tid >> 6;
    const int c4   = lane * 4;

    __shared__ __align__(16) float Xs[32][256];

    const size_t m0 = (size_t)mt * 32;
    #pragma unroll
    for (int j = 0; j < 8; ++j) {
        const int f4 = tid + j * 256;
        const int r  = f4 >> 6;
        const int k4 = (f4 & 63) * 4;
        *(float4*)&Xs[r][k4] = *(const float4*)(x + (m0 + r) * DIN + k4);
    }
    __syncthreads();

    float4 acc[8];
    const float4 bz = *(const float4*)(bias + c4);
    #pragma unroll
    for (int r = 0; r < 8; ++r) acc[r] = bz;

    #pragma unroll 4
    for (int k = 0; k < 256; ++k) {
        const float4 wv = *(const float4*)(W + (size_t)k * DC + c4);
        #pragma unroll
        for (int r = 0; r < 8; ++r) {
            const float xv = Xs[rg * 8 + r][k];
            acc[r].x += xv * wv.x; acc[r].y += xv * wv.y;
            acc[r].z += xv * wv.z; acc[r].w += xv * wv.w;
        }
    }
    #pragma unroll
    for (int r = 0; r < 8; ++r) {
        *(float4*)(P + (m0 + rg * 8 + r) * 768 + (size_t)g * 256 + c4) = acc[r];
    }
}

// ---------------------------------------------------------------------------
// Phase 2: recurrence, 512 threads (8 waves, 2 waves/SIMD) for latency
// hiding; 2 columns/thread (float2 loads). SPAIR=12 k-pairs/slice in LDS
// (144 KB stash, 156.5 KB LDS total). Streamed bytes/step:
// (20/32)*393KB = 246 KB + 3 KB P row. fp16 dot2 with fp32 accumulate.
// Writes RAW h into out[]; outproj applies Wout afterwards.
// ---------------------------------------------------------------------------
__global__ __launch_bounds__(512) void lstm_rec4(
    const float* __restrict__ P,    const float2* __restrict__ Wp2,
    const float* __restrict__ h0,   const float* __restrict__ c0,
    const int* __restrict__ Np,     float* __restrict__ out)
{
    const int b   = blockIdx.x;
    const int tid = threadIdx.x;
    const int sl  = tid >> 7;         // k-slice 0..3 (32 k-pairs each)
    const int l2  = tid & 127;        // 0..127
    const int c2  = l2 * 2;           // 2 adjacent output columns
    const int N   = *Np;

    __shared__ _Float16 combHh[DH];                    // 512 B
    __shared__ __align__(16) float part[3][4][DC];     // 12 KiB
    __shared__ float2 wst[4 * SPAIR][3][128];          // 144 KiB stash

    float c = 0.f, h_reg = 0.f;
    if (tid < 256) {
        c     = c0[b * DC + tid];
        h_reg = h0[b * DH + tid];
        combHh[tid] = (_Float16)h_reg;
    }

    const int k0h = sl * 32;          // k-pair base of this slice

    // fill stash: first SPAIR k-pairs of this slice, all 3 gates
    for (int j = 0; j < SPAIR; ++j) {
        #pragma unroll
        for (int g = 0; g < 3; ++g)
            wst[sl * SPAIR + j][g][l2] =
                Wp2[((size_t)g * 128 + k0h + j) * 128 + l2];
    }
    __syncthreads();

    const size_t pbase = (size_t)b * T_ * 768;
    const float2* Wf2 = Wp2 + ((size_t)0 * 128 + k0h) * 128 + l2;
    const float2* Wi2 = Wp2 + ((size_t)1 * 128 + k0h) * 128 + l2;
    const float2* Wo2 = Wp2 + ((size_t)2 * 128 + k0h) * 128 + l2;

    for (int t = 0; t < N; ++t) {
        // pre-activation row (x-part + bias), fp32 — only waves 0-3 need it
        float pf = 0.f, pi = 0.f, po = 0.f;
        if (tid < 256) {
            const size_t pr = pbase + (size_t)t * 768 + tid;
            pf = P[pr];
            pi = P[pr + 256];
            po = P[pr + 512];
        }

        float2 af = {0,0}, ai2 = {0,0}, ao2 = {0,0};

        // ---- LDS-stashed k-pairs ----
        #pragma unroll
        for (int j = 0; j < SPAIR; ++j) {
            const half2_t hk = *(const half2_t*)&combHh[(k0h + j) * 2];
            float2 rf = wst[sl * SPAIR + j][0][l2];
            float2 ri = wst[sl * SPAIR + j][1][l2];
            float2 ro = wst[sl * SPAIR + j][2][l2];
            const half2_t* wf = (const half2_t*)&rf;
            const half2_t* wi = (const half2_t*)&ri;
            const half2_t* wo = (const half2_t*)&ro;
            af.x  = FDOT2(wf[0], hk, af.x);  af.y  = FDOT2(wf[1], hk, af.y);
            ai2.x = FDOT2(wi[0], hk, ai2.x); ai2.y = FDOT2(wi[1], hk, ai2.y);
            ao2.x = FDOT2(wo[0], hk, ao2.x); ao2.y = FDOT2(wo[1], hk, ao2.y);
        }
        // ---- streamed k-pairs (L2-resident fp16 weights) ----
        #pragma unroll 4
        for (int j = SPAIR; j < 32; ++j) {
            const half2_t hk = *(const half2_t*)&combHh[(k0h + j) * 2];
            float2 rf = Wf2[(size_t)j * 128];
            float2 ri = Wi2[(size_t)j * 128];
            float2 ro = Wo2[(size_t)j * 128];
            const half2_t* wf = (const half2_t*)&rf;
            const half2_t* wi = (const half2_t*)&ri;
            const half2_t* wo = (const half2_t*)&ro;
            af.x  = FDOT2(wf[0], hk, af.x);  af.y  = FDOT2(wf[1], hk, af.y);
            ai2.x = FDOT2(wi[0], hk, ai2.x); ai2.y = FDOT2(wi[1], hk, ai2.y);
            ao2.x = FDOT2(wo[0], hk, ao2.x); ao2.y = FDOT2(wo[1], hk, ao2.y);
        }
        *(float2*)&part[0][sl][c2] = af;
        *(float2*)&part[1][sl][c2] = ai2;
        *(float2*)&part[2][sl][c2] = ao2;
        __syncthreads();

        // ---- per-column gate math (waves 0-3; thread tid owns column tid) --
        if (tid < 256) {
            const int n = tid;
            float fp = pf + part[0][0][n] + part[0][1][n] + part[0][2][n] + part[0][3][n];
            float ip = pi + part[1][0][n] + part[1][1][n] + part[1][2][n] + part[1][3][n];
            float op = po + part[2][0][n] + part[2][1][n] + part[2][2][n] + part[2][3][n];
            const float f = sigmoidf_(fp);
            const float i = sigmoidf_(ip);
            const float z = tanhf_(ip);      // pre_i reused for tanh per ref
            const float o = sigmoidf_(op);
            c     = c * f + z * i;
            h_reg = tanhf_(c) * o;
            combHh[n] = (_Float16)h_reg;                 // publish h_{t+1}
            out[((size_t)b * N + t) * DOUT + n] = h_reg; // raw h
        }
        __syncthreads();                 // combHh/part stable before next iter
    }

    // finals: d_out = [ outs (B*N*DOUT) | h_final (B*DH) | c_final (B*DC) ]
    if (tid < 256) {
        float* hf = out + (size_t)B_ * N * DOUT;
        float* cf = hf + (size_t)B_ * DH;
        hf[b * DH + tid] = h_reg;
        cf[b * DC + tid] = c;
    }
}

// ---------------------------------------------------------------------------
// Phase 3: in-place out[m,:] = sigmoid(out[m,:] @ Wout + bout), 32 rows/block.
// ---------------------------------------------------------------------------
__global__ __launch_bounds__(256) void outproj(
    const float* __restrict__ Wout, const float* __restrict__ bout,
    const int* __restrict__ Np, float* __restrict__ out)
{
    const int N = *Np;
    const size_t m0 = (size_t)blockIdx.x * 32;
    if (m0 >= (size_t)B_ * N) return;

    const int tid  = threadIdx.x;
    const int lane = tid & 63;
    const int rg   = tid >> 6;
    const int c4   = lane * 4;

    __shared__ __align__(16) float Hs[32][256];

    #pragma unroll
    for (int j = 0; j < 8; ++j) {
        const int f4 = tid + j * 256;
        const int r  = f4 >> 6;
        const int k4 = (f4 & 63) * 4;
        *(float4*)&Hs[r][k4] = *(const float4*)(out + (m0 + r) * DOUT + k4);
    }
    __syncthreads();

    float4 acc[8];
    const float4 bz = *(const float4*)(bout + c4);
    #pragma unroll
    for (int r = 0; r < 8; ++r) acc[r] = bz;

    #pragma unroll 4
    for (int k = 0; k < 256; ++k) {
        const float4 wv = *(const float4*)(Wout + (size_t)k * DOUT + c4);
        #pragma unroll
        for (int r = 0; r < 8; ++r) {
            const float hv = Hs[rg * 8 + r][k];
            acc[r].x += hv * wv.x; acc[r].y += hv * wv.y;
            acc[r].z += hv * wv.z; acc[r].w += hv * wv.w;
        }
    }
    #pragma unroll
    for (int r = 0; r < 8; ++r) {
        float4 q;
        q.x = sigmoidf_(acc[r].x); q.y = sigmoidf_(acc[r].y);
        q.z = sigmoidf_(acc[r].z); q.w = sigmoidf_(acc[r].w);
        *(float4*)(out + (m0 + rg * 8 + r) * DOUT + c4) = q;
    }
}

// ---------------------------------------------------------------------------
// Fallback: round-0 kernel (proven 28 ms) if workspace is too small.
// ---------------------------------------------------------------------------
__global__ __launch_bounds__(256) void lstm_persistent(
    const float* __restrict__ x,    const float* __restrict__ h0,
    const float* __restrict__ c0,   const float* __restrict__ Wf,
    const float* __restrict__ bf,   const float* __restrict__ Wi,
    const float* __restrict__ bi,   const float* __restrict__ Wo,
    const float* __restrict__ bo,   const float* __restrict__ Wout,
    const float* __restrict__ bout, const int* __restrict__ Np,
    float* __restrict__ out)
{
    const int b   = blockIdx.x;
    const int tid = threadIdx.x;
    const int sl  = tid >> 6;
    const int cg  = (tid & 63) * 4;
    const int N   = *Np;

    __shared__ float comb[K2];
    __shared__ float part[3][4][DC];

    float c     = c0[b * DC + tid];
    float h_reg = h0[b * DH + tid];
    comb[DIN + tid] = h_reg;
    comb[tid]       = x[((size_t)b * T_ + 0) * DIN + tid];
    __syncthreads();

    const size_t xbase = (size_t)b * T_ * DIN;

    for (int t = 0; t < N; ++t) {
        float4 af = {0,0,0,0}, ai = {0,0,0,0}, ao = {0,0,0,0};
        const int k0 = sl * 128;
        #pragma unroll 4
        for (int k = k0; k < k0 + 128; ++k) {
            const float ck = comb[k];
            const float4 wf = *(const float4*)(Wf + (size_t)k * DC + cg);
            const float4 wi = *(const float4*)(Wi + (size_t)k * DC + cg);
            const float4 wo = *(const float4*)(Wo + (size_t)k * DC + cg);
            af.x += ck*wf.x; af.y += ck*wf.y; af.z += ck*wf.z; af.w += ck*wf.w;
            ai.x += ck*wi.x; ai.y += ck*wi.y; ai.z += ck*wi.z; ai.w += ck*wi.w;
            ao.x += ck*wo.x; ao.y += ck*wo.y; ao.z += ck*wo.z; ao.w += ck*wo.w;
        }
        *(float4*)&part[0][sl][cg] = af;
        *(float4*)&part[1][sl][cg] = ai;
        *(float4*)&part[2][sl][cg] = ao;
        __syncthreads();

        const int n = tid;
        float fp = bf[n] + part[0][0][n] + part[0][1][n] + part[0][2][n] + part[0][3][n];
        float ip = bi[n] + part[1][0][n] + part[1][1][n] + part[1][2][n] + part[1][3][n];
        float op = bo[n] + part[2][0][n] + part[2][1][n] + part[2][2][n] + part[2][3][n];
        const float f = sigmoidf_(fp);
        const float i = sigmoidf_(ip);
        const float z = tanhf_(ip);
        const float o = sigmoidf_(op);
        c     = c * f + z * i;
        h_reg = tanhf_(c) * o;
        __syncthreads();

        comb[DIN + n] = h_reg;
        if (t + 1 < N) comb[n] = x[xbase + (size_t)(t + 1) * DIN + n];
        __syncthreads();

        float4 aq = {0,0,0,0};
        const int q0 = sl * 64;
        #pragma unroll 4
        for (int k = q0; k < q0 + 64; ++k) {
            const float hk = comb[DIN + k];
            const float4 w = *(const float4*)(Wout + (size_t)k * DOUT + cg);
            aq.x += hk*w.x; aq.y += hk*w.y; aq.z += hk*w.z; aq.w += hk*w.w;
        }
        *(float4*)&part[0][sl][cg] = aq;
        __syncthreads();
        const float q = bout[n] + part[0][0][n] + part[0][1][n]
                                + part[0][2][n] + part[0][3][n];
        out[((size_t)b * N + t) * DOUT + n] = sigmoidf_(q);
        __syncthreads();
    }

    float* hf = out + (size_t)B_ * N * DOUT;
    float* cf = hf + (size_t)B_ * DH;
    hf[b * DH + tid] = h_reg;
    cf[b * DC + tid] = c;
}

extern "C" void kernel_launch(void* const* d_in, const int* in_sizes, int n_in,
                              void* d_out, int out_size, void* d_ws, size_t ws_size,
                              hipStream_t stream) {
    const float* x    = (const float*)d_in[0];
    const float* h0   = (const float*)d_in[1];
    const float* c0   = (const float*)d_in[2];
    const float* Wf   = (const float*)d_in[3];
    const float* bf   = (const float*)d_in[4];
    const float* Wi   = (const float*)d_in[5];
    const float* bi   = (const float*)d_in[6];
    const float* Wo   = (const float*)d_in[7];
    const float* bo   = (const float*)d_in[8];
    const float* Wout = (const float*)d_in[9];
    const float* bout = (const float*)d_in[10];
    const int*   Np   = (const int*)d_in[11];
    float* out = (float*)d_out;

    const size_t PSIZE  = (size_t)B_ * T_ * 768 * sizeof(float);   // 403 MB
    const size_t WPSIZE = (size_t)3 * 128 * 256 * 4;               // 393 KB
    if (ws_size >= PSIZE + WPSIZE) {
        float*   P  = (float*)d_ws;
        half2_t* Wp = (half2_t*)((char*)d_ws + PSIZE);
        hipLaunchKernelGGL(packw, dim3(3, 16), dim3(256), 0, stream,
                           Wf, Wi, Wo, Wp);
        hipLaunchKernelGGL(xgemm, dim3((B_ * T_) / 32, 3), dim3(256), 0, stream,
                           x, Wf, bf, Wi, bi, Wo, bo, P);
        hipLaunchKernelGGL(lstm_rec4, dim3(B_), dim3(512), 0, stream,
                           P, (const float2*)Wp, h0, c0, Np, out);
        hipLaunchKernelGGL(outproj, dim3((B_ * T_) / 32), dim3(256), 0, stream,
                           Wout, bout, Np, out);
    } else {
        hipLaunchKernelGGL(lstm_persistent, dim3(B_), dim3(256), 0, stream,
                           x, h0, c0, Wf, bf, Wi, bi, Wo, bo, Wout, bout, Np, out);
    }
}

// Round 7
// 6426.936 us; speedup vs baseline: 1.5478x; 1.5478x over previous
//
#include <hip/hip_runtime.h>
#include <math.h>

// Problem constants (match reference)
#define B_    64
#define T_    2048
#define DIN   256
#define DH    256
#define DC    256
#define DOUT  256
#define K2    512   // DIN + DH
#define LDSP  11    // k-pairs per slice stashed in LDS
#define REGP  12    // k-pairs per slice stashed in VGPRs
// streamed per slice = 32 - LDSP - REGP = 9

typedef _Float16 half2_t __attribute__((ext_vector_type(2)));

#if defined(__has_builtin)
#  if __has_builtin(__builtin_amdgcn_fdot2)
#    define FDOT2(a,b,c) __builtin_amdgcn_fdot2((a),(b),(c),false)
#  endif
#endif
#ifndef FDOT2   // scalar fallback if builtin unavailable
#  define FDOT2(a,b,c) ((c) + (float)(a)[0]*(float)(b)[0] + (float)(a)[1]*(float)(b)[1])
#endif

__device__ __forceinline__ float sigmoidf_(float x) {
    return 1.0f / (1.0f + __expf(-x));
}

__device__ __forceinline__ float tanhf_(float x) {
    float ax = fabsf(x);
    float e  = __expf(-2.0f * ax);
    float t  = (1.0f - e) / (1.0f + e);
    return copysignf(t, x);
}

// ---------------------------------------------------------------------------
// Phase 0: pack h-half gate weights to fp16 k-pairs.
// Wp[g][k2][n] = ( W[256+2k2][n], W[256+2k2+1][n] ) as half2. 393 KB total.
// ---------------------------------------------------------------------------
__global__ __launch_bounds__(256) void packw(
    const float* __restrict__ Wf, const float* __restrict__ Wi,
    const float* __restrict__ Wo, half2_t* __restrict__ Wp)
{
    const int g     = blockIdx.x;        // gate 0..2
    const int chunk = blockIdx.y;        // 16 chunks x 8 k-pairs
    const int n     = threadIdx.x;
    const float* W = ((g == 0) ? Wf : (g == 1) ? Wi : Wo) + (size_t)DIN * DC;
    #pragma unroll
    for (int j = 0; j < 8; ++j) {
        const int k2 = chunk * 8 + j;
        half2_t p;
        p[0] = (_Float16)W[(size_t)(2 * k2)     * DC + n];
        p[1] = (_Float16)W[(size_t)(2 * k2 + 1) * DC + n];
        Wp[((size_t)g * 128 + k2) * 256 + n] = p;
    }
}

// ---------------------------------------------------------------------------
// Phase 1: P[b,t,g*256+n] = x[b,t,:] @ Wg[0:256,:] + bg   (no recurrence)
// ---------------------------------------------------------------------------
__global__ __launch_bounds__(256) void xgemm(
    const float* __restrict__ x,
    const float* __restrict__ Wf, const float* __restrict__ bf,
    const float* __restrict__ Wi, const float* __restrict__ bi,
    const float* __restrict__ Wo, const float* __restrict__ bo,
    float* __restrict__ P)
{
    const int mt  = blockIdx.x;
    const int g   = blockIdx.y;
    const float* W    = (g == 0) ? Wf : (g == 1) ? Wi : Wo;
    const float* bias = (g == 0) ? bf : (g == 1) ? bi : bo;
    const int tid  = threadIdx.x;
    const int lane = tid & 63;
    const int rg   = tid >> 6;
    const int c4   = lane * 4;

    __shared__ __align__(16) float Xs[32][256];

    const size_t m0 = (size_t)mt * 32;
    #pragma unroll
    for (int j = 0; j < 8; ++j) {
        const int f4 = tid + j * 256;
        const int r  = f4 >> 6;
        const int k4 = (f4 & 63) * 4;
        *(float4*)&Xs[r][k4] = *(const float4*)(x + (m0 + r) * DIN + k4);
    }
    __syncthreads();

    float4 acc[8];
    const float4 bz = *(const float4*)(bias + c4);
    #pragma unroll
    for (int r = 0; r < 8; ++r) acc[r] = bz;

    #pragma unroll 4
    for (int k = 0; k < 256; ++k) {
        const float4 wv = *(const float4*)(W + (size_t)k * DC + c4);
        #pragma unroll
        for (int r = 0; r < 8; ++r) {
            const float xv = Xs[rg * 8 + r][k];
            acc[r].x += xv * wv.x; acc[r].y += xv * wv.y;
            acc[r].z += xv * wv.z; acc[r].w += xv * wv.w;
        }
    }
    #pragma unroll
    for (int r = 0; r < 8; ++r) {
        *(float4*)(P + (m0 + rg * 8 + r) * 768 + (size_t)g * 256 + c4) = acc[r];
    }
}

// ---------------------------------------------------------------------------
// Phase 2: recurrence. Per-step cost model (fit on 6 rounds):
//   T = 16.2 cyc * (wave load-insts per CU) + overhead.
// So: minimize REQUESTS. 12 k-pairs/slice in VGPRs (statically indexed),
// 11 in LDS, only 9 streamed -> 27 f4 loads + 3 P loads + 1 store per
// thread per step. ONE barrier per step: combH is wave-private (wave sl
// reads exactly h-columns [64sl,64sl+64) its own threads produce), so only
// part[] needs cross-wave protection -> double-buffer part[], drop the
// second barrier; waves issue next-step loads while others finish gates.
// ---------------------------------------------------------------------------
__global__ __launch_bounds__(256, 1) void lstm_rec5(
    const float* __restrict__ P,    const float4* __restrict__ Wp4,
    const float* __restrict__ h0,   const float* __restrict__ c0,
    const int* __restrict__ Np,     float* __restrict__ out)
{
    const int b    = blockIdx.x;
    const int tid  = threadIdx.x;
    const int sl   = tid >> 6;        // k-slice 0..3 (32 k-pairs each)
    const int lane = tid & 63;
    const int cg   = lane * 4;        // 4 adjacent output columns
    const int N    = *Np;

    __shared__ _Float16 combHh[DH];                     // 512 B
    __shared__ __align__(16) float part[2][3][4][DC];   // 24 KiB (dbuf)
    __shared__ float4 wst[4 * LDSP][3][64];             // 132 KiB stash

    float c     = c0[b * DC + tid];
    float h_reg = h0[b * DH + tid];
    combHh[tid] = (_Float16)h_reg;

    const int k0h = sl * 32;          // k-pair base of this slice

    // LDS stash: k-pairs [k0h, k0h+LDSP), all 3 gates
    for (int j = 0; j < LDSP; ++j) {
        #pragma unroll
        for (int g = 0; g < 3; ++g)
            wst[sl * LDSP + j][g][lane] =
                Wp4[((size_t)g * 128 + k0h + j) * 64 + lane];
    }

    // VGPR stash: k-pairs [k0h+LDSP, k0h+LDSP+REGP), all 3 gates (144 VGPRs)
    float4 wreg[REGP][3];
    #pragma unroll
    for (int j = 0; j < REGP; ++j) {
        #pragma unroll
        for (int g = 0; g < 3; ++g)
            wreg[j][g] = Wp4[((size_t)g * 128 + k0h + LDSP + j) * 64 + lane];
    }
    __syncthreads();

    const size_t pbase = (size_t)b * T_ * 768;
    // streamed base pointers (k-pairs [k0h+LDSP+REGP, k0h+32))
    const float4* Wf4 = Wp4 + ((size_t)0 * 128 + k0h) * 64 + lane;
    const float4* Wi4 = Wp4 + ((size_t)1 * 128 + k0h) * 64 + lane;
    const float4* Wo4 = Wp4 + ((size_t)2 * 128 + k0h) * 64 + lane;

    for (int t = 0; t < N; ++t) {
        const int buf = t & 1;
        // pre-activation row (x-part + bias); latency hidden under dot loop
        const size_t pr = pbase + (size_t)t * 768 + tid;
        const float pf = P[pr];
        const float pi = P[pr + 256];
        const float po = P[pr + 512];

        float4 af = {0,0,0,0}, ai4 = {0,0,0,0}, ao4 = {0,0,0,0};

        // ---- streamed k-pairs FIRST (issue loads asap, overlap gate math
        //      of other waves still in step t-1) ----
        #pragma unroll
        for (int j = LDSP + REGP; j < 32; ++j) {
            const half2_t hk = *(const half2_t*)&combHh[(k0h + j) * 2];
            float4 rf = Wf4[(size_t)j * 64];
            float4 ri = Wi4[(size_t)j * 64];
            float4 ro = Wo4[(size_t)j * 64];
            const half2_t* wf = (const half2_t*)&rf;
            const half2_t* wi = (const half2_t*)&ri;
            const half2_t* wo = (const half2_t*)&ro;
            af.x  = FDOT2(wf[0], hk, af.x);  af.y  = FDOT2(wf[1], hk, af.y);
            af.z  = FDOT2(wf[2], hk, af.z);  af.w  = FDOT2(wf[3], hk, af.w);
            ai4.x = FDOT2(wi[0], hk, ai4.x); ai4.y = FDOT2(wi[1], hk, ai4.y);
            ai4.z = FDOT2(wi[2], hk, ai4.z); ai4.w = FDOT2(wi[3], hk, ai4.w);
            ao4.x = FDOT2(wo[0], hk, ao4.x); ao4.y = FDOT2(wo[1], hk, ao4.y);
            ao4.z = FDOT2(wo[2], hk, ao4.z); ao4.w = FDOT2(wo[3], hk, ao4.w);
        }
        // ---- VGPR-stashed k-pairs (zero memory traffic) ----
        #pragma unroll
        for (int j = 0; j < REGP; ++j) {
            const half2_t hk = *(const half2_t*)&combHh[(k0h + LDSP + j) * 2];
            const half2_t* wf = (const half2_t*)&wreg[j][0];
            const half2_t* wi = (const half2_t*)&wreg[j][1];
            const half2_t* wo = (const half2_t*)&wreg[j][2];
            af.x  = FDOT2(wf[0], hk, af.x);  af.y  = FDOT2(wf[1], hk, af.y);
            af.z  = FDOT2(wf[2], hk, af.z);  af.w  = FDOT2(wf[3], hk, af.w);
            ai4.x = FDOT2(wi[0], hk, ai4.x); ai4.y = FDOT2(wi[1], hk, ai4.y);
            ai4.z = FDOT2(wi[2], hk, ai4.z); ai4.w = FDOT2(wi[3], hk, ai4.w);
            ao4.x = FDOT2(wo[0], hk, ao4.x); ao4.y = FDOT2(wo[1], hk, ao4.y);
            ao4.z = FDOT2(wo[2], hk, ao4.z); ao4.w = FDOT2(wo[3], hk, ao4.w);
        }
        // ---- LDS-stashed k-pairs (DS pipe, overlaps VMEM) ----
        #pragma unroll
        for (int j = 0; j < LDSP; ++j) {
            const half2_t hk = *(const half2_t*)&combHh[(k0h + j) * 2];
            float4 rf = wst[sl * LDSP + j][0][lane];
            float4 ri = wst[sl * LDSP + j][1][lane];
            float4 ro = wst[sl * LDSP + j][2][lane];
            const half2_t* wf = (const half2_t*)&rf;
            const half2_t* wi = (const half2_t*)&ri;
            const half2_t* wo = (const half2_t*)&ro;
            af.x  = FDOT2(wf[0], hk, af.x);  af.y  = FDOT2(wf[1], hk, af.y);
            af.z  = FDOT2(wf[2], hk, af.z);  af.w  = FDOT2(wf[3], hk, af.w);
            ai4.x = FDOT2(wi[0], hk, ai4.x); ai4.y = FDOT2(wi[1], hk, ai4.y);
            ai4.z = FDOT2(wi[2], hk, ai4.z); ai4.w = FDOT2(wi[3], hk, ai4.w);
            ao4.x = FDOT2(wo[0], hk, ao4.x); ao4.y = FDOT2(wo[1], hk, ao4.y);
            ao4.z = FDOT2(wo[2], hk, ao4.z); ao4.w = FDOT2(wo[3], hk, ao4.w);
        }

        *(float4*)&part[buf][0][sl][cg] = af;
        *(float4*)&part[buf][1][sl][cg] = ai4;
        *(float4*)&part[buf][2][sl][cg] = ao4;
        __syncthreads();   // the ONLY barrier: part[buf] write -> read

        // ---- per-column gate math (thread tid owns column tid) ----
        // Reads part[buf] (all slices); writes combHh[tid] (wave-private:
        // consumed only by this thread's own wave next step). Next step
        // writes part[buf^1] -> no trailing barrier needed; a lagging
        // wave's part[buf] reads are protected by the NEXT step's barrier
        // before anyone re-writes part[buf].
        const int n = tid;
        float fp = pf + part[buf][0][0][n] + part[buf][0][1][n]
                      + part[buf][0][2][n] + part[buf][0][3][n];
        float ip = pi + part[buf][1][0][n] + part[buf][1][1][n]
                      + part[buf][1][2][n] + part[buf][1][3][n];
        float op = po + part[buf][2][0][n] + part[buf][2][1][n]
                      + part[buf][2][2][n] + part[buf][2][3][n];
        const float f = sigmoidf_(fp);
        const float i = sigmoidf_(ip);
        const float z = tanhf_(ip);      // pre_i reused for tanh per reference
        const float o = sigmoidf_(op);
        c     = c * f + z * i;
        h_reg = tanhf_(c) * o;
        combHh[n] = (_Float16)h_reg;                 // wave-private publish
        out[((size_t)b * N + t) * DOUT + n] = h_reg; // raw h; outproj fixes up
    }

    // finals: d_out = [ outs (B*N*DOUT) | h_final (B*DH) | c_final (B*DC) ]
    float* hf = out + (size_t)B_ * N * DOUT;
    float* cf = hf + (size_t)B_ * DH;
    hf[b * DH + tid] = h_reg;
    cf[b * DC + tid] = c;
}

// ---------------------------------------------------------------------------
// Phase 3: in-place out[m,:] = sigmoid(out[m,:] @ Wout + bout), 32 rows/block.
// ---------------------------------------------------------------------------
__global__ __launch_bounds__(256) void outproj(
    const float* __restrict__ Wout, const float* __restrict__ bout,
    const int* __restrict__ Np, float* __restrict__ out)
{
    const int N = *Np;
    const size_t m0 = (size_t)blockIdx.x * 32;
    if (m0 >= (size_t)B_ * N) return;

    const int tid  = threadIdx.x;
    const int lane = tid & 63;
    const int rg   = tid >> 6;
    const int c4   = lane * 4;

    __shared__ __align__(16) float Hs[32][256];

    #pragma unroll
    for (int j = 0; j < 8; ++j) {
        const int f4 = tid + j * 256;
        const int r  = f4 >> 6;
        const int k4 = (f4 & 63) * 4;
        *(float4*)&Hs[r][k4] = *(const float4*)(out + (m0 + r) * DOUT + k4);
    }
    __syncthreads();

    float4 acc[8];
    const float4 bz = *(const float4*)(bout + c4);
    #pragma unroll
    for (int r = 0; r < 8; ++r) acc[r] = bz;

    #pragma unroll 4
    for (int k = 0; k < 256; ++k) {
        const float4 wv = *(const float4*)(Wout + (size_t)k * DOUT + c4);
        #pragma unroll
        for (int r = 0; r < 8; ++r) {
            const float hv = Hs[rg * 8 + r][k];
            acc[r].x += hv * wv.x; acc[r].y += hv * wv.y;
            acc[r].z += hv * wv.z; acc[r].w += hv * wv.w;
        }
    }
    #pragma unroll
    for (int r = 0; r < 8; ++r) {
        float4 q;
        q.x = sigmoidf_(acc[r].x); q.y = sigmoidf_(acc[r].y);
        q.z = sigmoidf_(acc[r].z); q.w = sigmoidf_(acc[r].w);
        *(float4*)(out + (m0 + rg * 8 + r) * DOUT + c4) = q;
    }
}

// ---------------------------------------------------------------------------
// Fallback: round-0 kernel (proven 28 ms) if workspace is too small.
// ---------------------------------------------------------------------------
__global__ __launch_bounds__(256) void lstm_persistent(
    const float* __restrict__ x,    const float* __restrict__ h0,
    const float* __restrict__ c0,   const float* __restrict__ Wf,
    const float* __restrict__ bf,   const float* __restrict__ Wi,
    const float* __restrict__ bi,   const float* __restrict__ Wo,
    const float* __restrict__ bo,   const float* __restrict__ Wout,
    const float* __restrict__ bout, const int* __restrict__ Np,
    float* __restrict__ out)
{
    const int b   = blockIdx.x;
    const int tid = threadIdx.x;
    const int sl  = tid >> 6;
    const int cg  = (tid & 63) * 4;
    const int N   = *Np;

    __shared__ float comb[K2];
    __shared__ float part[3][4][DC];

    float c     = c0[b * DC + tid];
    float h_reg = h0[b * DH + tid];
    comb[DIN + tid] = h_reg;
    comb[tid]       = x[((size_t)b * T_ + 0) * DIN + tid];
    __syncthreads();

    const size_t xbase = (size_t)b * T_ * DIN;

    for (int t = 0; t < N; ++t) {
        float4 af = {0,0,0,0}, ai = {0,0,0,0}, ao = {0,0,0,0};
        const int k0 = sl * 128;
        #pragma unroll 4
        for (int k = k0; k < k0 + 128; ++k) {
            const float ck = comb[k];
            const float4 wf = *(const float4*)(Wf + (size_t)k * DC + cg);
            const float4 wi = *(const float4*)(Wi + (size_t)k * DC + cg);
            const float4 wo = *(const float4*)(Wo + (size_t)k * DC + cg);
            af.x += ck*wf.x; af.y += ck*wf.y; af.z += ck*wf.z; af.w += ck*wf.w;
            ai.x += ck*wi.x; ai.y += ck*wi.y; ai.z += ck*wi.z; ai.w += ck*wi.w;
            ao.x += ck*wo.x; ao.y += ck*wo.y; ao.z += ck*wo.z; ao.w += ck*wo.w;
        }
        *(float4*)&part[0][sl][cg] = af;
        *(float4*)&part[1][sl][cg] = ai;
        *(float4*)&part[2][sl][cg] = ao;
        __syncthreads();

        const int n = tid;
        float fp = bf[n] + part[0][0][n] + part[0][1][n] + part[0][2][n] + part[0][3][n];
        float ip = bi[n] + part[1][0][n] + part[1][1][n] + part[1][2][n] + part[1][3][n];
        float op = bo[n] + part[2][0][n] + part[2][1][n] + part[2][2][n] + part[2][3][n];
        const float f = sigmoidf_(fp);
        const float i = sigmoidf_(ip);
        const float z = tanhf_(ip);
        const float o = sigmoidf_(op);
        c     = c * f + z * i;
        h_reg = tanhf_(c) * o;
        __syncthreads();

        comb[DIN + n] = h_reg;
        if (t + 1 < N) comb[n] = x[xbase + (size_t)(t + 1) * DIN + n];
        __syncthreads();

        float4 aq = {0,0,0,0};
        const int q0 = sl * 64;
        #pragma unroll 4
        for (int k = q0; k < q0 + 64; ++k) {
            const float hk = comb[DIN + k];
            const float4 w = *(const float4*)(Wout + (size_t)k * DOUT + cg);
            aq.x += hk*w.x; aq.y += hk*w.y; aq.z += hk*w.z; aq.w += hk*w.w;
        }
        *(float4*)&part[0][sl][cg] = aq;
        __syncthreads();
        const float q = bout[n] + part[0][0][n] + part[0][1][n]
                                + part[0][2][n] + part[0][3][n];
        out[((size_t)b * N + t) * DOUT + n] = sigmoidf_(q);
        __syncthreads();
    }

    float* hf = out + (size_t)B_ * N * DOUT;
    float* cf = hf + (size_t)B_ * DH;
    hf[b * DH + tid] = h_reg;
    cf[b * DC + tid] = c;
}

extern "C" void kernel_launch(void* const* d_in, const int* in_sizes, int n_in,
                              void* d_out, int out_size, void* d_ws, size_t ws_size,
                              hipStream_t stream) {
    const float* x    = (const float*)d_in[0];
    const float* h0   = (const float*)d_in[1];
    const float* c0   = (const float*)d_in[2];
    const float* Wf   = (const float*)d_in[3];
    const float* bf   = (const float*)d_in[4];
    const float* Wi   = (const float*)d_in[5];
    const float* bi   = (const float*)d_in[6];
    const float* Wo   = (const float*)d_in[7];
    const float* bo   = (const float*)d_in[8];
    const float* Wout = (const float*)d_in[9];
    const float* bout = (const float*)d_in[10];
    const int*   Np   = (const int*)d_in[11];
    float* out = (float*)d_out;

    const size_t PSIZE  = (size_t)B_ * T_ * 768 * sizeof(float);   // 403 MB
    const size_t WPSIZE = (size_t)3 * 128 * 256 * 4;               // 393 KB
    if (ws_size >= PSIZE + WPSIZE) {
        float*   P  = (float*)d_ws;
        half2_t* Wp = (half2_t*)((char*)d_ws + PSIZE);
        hipLaunchKernelGGL(packw, dim3(3, 16), dim3(256), 0, stream,
                           Wf, Wi, Wo, Wp);
        hipLaunchKernelGGL(xgemm, dim3((B_ * T_) / 32, 3), dim3(256), 0, stream,
                           x, Wf, bf, Wi, bi, Wo, bo, P);
        hipLaunchKernelGGL(lstm_rec5, dim3(B_), dim3(256), 0, stream,
                           P, (const float4*)Wp, h0, c0, Np, out);
        hipLaunchKernelGGL(outproj, dim3((B_ * T_) / 32), dim3(256), 0, stream,
                           Wout, bout, Np, out);
    } else {
        hipLaunchKernelGGL(lstm_persistent, dim3(B_), dim3(256), 0, stream,
                           x, h0, c0, Wf, bf, Wi, bi, Wo, bo, Wout, bout, Np, out);
    }
}

// Round 10
// 6422.384 us; speedup vs baseline: 1.5489x; 1.0007x over previous
//
#include <hip/hip_runtime.h>
#include <math.h>

// Problem constants (match reference)
#define B_    64
#define T_    2048
#define DIN   256
#define DH    256
#define DC    256
#define DOUT  256
#define K2    512   // DIN + DH
#define LDSP  11    // k-pairs per slice stashed in LDS
#define REGP  21    // k-pairs per slice stashed in VGPRs -> ZERO streamed

typedef _Float16 half2_t __attribute__((ext_vector_type(2)));

#if defined(__has_builtin)
#  if __has_builtin(__builtin_amdgcn_fdot2)
#    define FDOT2(a,b,c) __builtin_amdgcn_fdot2((a),(b),(c),false)
#  endif
#endif
#ifndef FDOT2   // scalar fallback if builtin unavailable
#  define FDOT2(a,b,c) ((c) + (float)(a)[0]*(float)(b)[0] + (float)(a)[1]*(float)(b)[1])
#endif

__device__ __forceinline__ float sigmoidf_(float x) {
    return 1.0f / (1.0f + __expf(-x));
}

__device__ __forceinline__ float tanhf_(float x) {
    float ax = fabsf(x);
    float e  = __expf(-2.0f * ax);
    float t  = (1.0f - e) / (1.0f + e);
    return copysignf(t, x);
}

// ---------------------------------------------------------------------------
// Phase 0: pack h-half gate weights to fp16 k-pairs.
// Wp[g][k2][n] = ( W[256+2k2][n], W[256+2k2+1][n] ) as half2. 393 KB total.
// ---------------------------------------------------------------------------
__global__ __launch_bounds__(256) void packw(
    const float* __restrict__ Wf, const float* __restrict__ Wi,
    const float* __restrict__ Wo, half2_t* __restrict__ Wp)
{
    const int g     = blockIdx.x;        // gate 0..2
    const int chunk = blockIdx.y;        // 16 chunks x 8 k-pairs
    const int n     = threadIdx.x;
    const float* W = ((g == 0) ? Wf : (g == 1) ? Wi : Wo) + (size_t)DIN * DC;
    #pragma unroll
    for (int j = 0; j < 8; ++j) {
        const int k2 = chunk * 8 + j;
        half2_t p;
        p[0] = (_Float16)W[(size_t)(2 * k2)     * DC + n];
        p[1] = (_Float16)W[(size_t)(2 * k2 + 1) * DC + n];
        Wp[((size_t)g * 128 + k2) * 256 + n] = p;
    }
}

// ---------------------------------------------------------------------------
// Phase 1: P[b,t,g*256+n] = x[b,t,:] @ Wg[0:256,:] + bg   (no recurrence)
// ---------------------------------------------------------------------------
__global__ __launch_bounds__(256) void xgemm(
    const float* __restrict__ x,
    const float* __restrict__ Wf, const float* __restrict__ bf,
    const float* __restrict__ Wi, const float* __restrict__ bi,
    const float* __restrict__ Wo, const float* __restrict__ bo,
    float* __restrict__ P)
{
    const int mt  = blockIdx.x;
    const int g   = blockIdx.y;
    const float* W    = (g == 0) ? Wf : (g == 1) ? Wi : Wo;
    const float* bias = (g == 0) ? bf : (g == 1) ? bi : bo;
    const int tid  = threadIdx.x;
    const int lane = tid & 63;
    const int rg   = tid >> 6;
    const int c4   = lane * 4;

    __shared__ __align__(16) float Xs[32][256];

    const size_t m0 = (size_t)mt * 32;
    #pragma unroll
    for (int j = 0; j < 8; ++j) {
        const int f4 = tid + j * 256;
        const int r  = f4 >> 6;
        const int k4 = (f4 & 63) * 4;
        *(float4*)&Xs[r][k4] = *(const float4*)(x + (m0 + r) * DIN + k4);
    }
    __syncthreads();

    float4 acc[8];
    const float4 bz = *(const float4*)(bias + c4);
    #pragma unroll
    for (int r = 0; r < 8; ++r) acc[r] = bz;

    #pragma unroll 4
    for (int k = 0; k < 256; ++k) {
        const float4 wv = *(const float4*)(W + (size_t)k * DC + c4);
        #pragma unroll
        for (int r = 0; r < 8; ++r) {
            const float xv = Xs[rg * 8 + r][k];
            acc[r].x += xv * wv.x; acc[r].y += xv * wv.y;
            acc[r].z += xv * wv.z; acc[r].w += xv * wv.w;
        }
    }
    #pragma unroll
    for (int r = 0; r < 8; ++r) {
        *(float4*)(P + (m0 + rg * 8 + r) * 768 + (size_t)g * 256 + c4) = acc[r];
    }
}

// ---------------------------------------------------------------------------
// Phase 2: recurrence. Cost law (fit to 7 rounds, <=5% err):
//   cyc/step = 16.2 * (per-CU wave load-insts) + ~2k.
// This version: ALL weights on-chip. 11 k-pairs/slice in LDS (132 KB),
// 21 k-pairs/slice in VGPRs (252 VGPRs of fp16, NAMED scalars + per-
// component asm pins + unreachable post-loop consumer so the allocator
// cannot demote them — R7's VGPR_Count=152 proved plain code gets
// rematerialized into per-step L2 loads; R9 proved "+v" on a full float4
// doesn't compile, so pins are per 32-bit component). Loop global traffic:
// 3 P loads + 1 h store per thread per step. One barrier per step
// (part[] double-buffered; combHh is wave-private).
// ---------------------------------------------------------------------------
#define FOR_REGP(M) M(0) M(1) M(2) M(3) M(4) M(5) M(6) M(7) M(8) M(9) M(10) \
                    M(11) M(12) M(13) M(14) M(15) M(16) M(17) M(18) M(19) M(20)

#define DECLW(j) \
    float4 wf##j = Wp4[((size_t)0 * 128 + k0h + LDSP + j) * 64 + lane]; \
    float4 wi##j = Wp4[((size_t)1 * 128 + k0h + LDSP + j) * 64 + lane]; \
    float4 wo##j = Wp4[((size_t)2 * 128 + k0h + LDSP + j) * 64 + lane]; \
    asm volatile("" : "+v"(wf##j.x), "+v"(wf##j.y), "+v"(wf##j.z), "+v"(wf##j.w), \
                      "+v"(wi##j.x), "+v"(wi##j.y), "+v"(wi##j.z), "+v"(wi##j.w), \
                      "+v"(wo##j.x), "+v"(wo##j.y), "+v"(wo##j.z), "+v"(wo##j.w));

#define DOTW(j) { \
    const half2_t hk = *(const half2_t*)&combHh[(k0h + LDSP + j) * 2]; \
    const half2_t* wfp = (const half2_t*)&wf##j; \
    const half2_t* wip = (const half2_t*)&wi##j; \
    const half2_t* wop = (const half2_t*)&wo##j; \
    af.x  = FDOT2(wfp[0], hk, af.x);  af.y  = FDOT2(wfp[1], hk, af.y); \
    af.z  = FDOT2(wfp[2], hk, af.z);  af.w  = FDOT2(wfp[3], hk, af.w); \
    ai4.x = FDOT2(wip[0], hk, ai4.x); ai4.y = FDOT2(wip[1], hk, ai4.y); \
    ai4.z = FDOT2(wip[2], hk, ai4.z); ai4.w = FDOT2(wip[3], hk, ai4.w); \
    ao4.x = FDOT2(wop[0], hk, ao4.x); ao4.y = FDOT2(wop[1], hk, ao4.y); \
    ao4.z = FDOT2(wop[2], hk, ao4.z); ao4.w = FDOT2(wop[3], hk, ao4.w); }

#define KEEPW(j) s += wf##j.x + wi##j.y + wo##j.w;

__global__ __launch_bounds__(256, 1) void lstm_rec6(
    const float* __restrict__ P,    const float4* __restrict__ Wp4,
    const float* __restrict__ h0,   const float* __restrict__ c0,
    const int* __restrict__ Np,     float* __restrict__ out)
{
    const int b    = blockIdx.x;
    const int tid  = threadIdx.x;
    const int sl   = tid >> 6;        // k-slice 0..3 (32 k-pairs each)
    const int lane = tid & 63;
    const int cg   = lane * 4;        // 4 adjacent output columns
    const int N    = *Np;

    __shared__ _Float16 combHh[DH];                     // 512 B
    __shared__ __align__(16) float part[2][3][4][DC];   // 24 KiB (dbuf)
    __shared__ float4 wst[4 * LDSP][3][64];             // 132 KiB stash

    float c     = c0[b * DC + tid];
    float h_reg = h0[b * DH + tid];
    combHh[tid] = (_Float16)h_reg;

    const int k0h = sl * 32;          // k-pair base of this slice

    // LDS stash: k-pairs [k0h, k0h+LDSP), all 3 gates
    for (int j = 0; j < LDSP; ++j) {
        #pragma unroll
        for (int g = 0; g < 3; ++g)
            wst[sl * LDSP + j][g][lane] =
                Wp4[((size_t)g * 128 + k0h + j) * 64 + lane];
    }

    // VGPR stash: k-pairs [k0h+LDSP, k0h+32), all 3 gates — 252 VGPRs,
    // named scalars, pinned per component.
    FOR_REGP(DECLW)
    __syncthreads();

    const size_t pbase = (size_t)b * T_ * 768;

    for (int t = 0; t < N; ++t) {
        const int buf = t & 1;
        // the ONLY per-step global loads: pre-activation row (x-part + bias)
        const size_t pr = pbase + (size_t)t * 768 + tid;
        const float pf = P[pr];
        const float pi = P[pr + 256];
        const float po = P[pr + 512];

        float4 af = {0,0,0,0}, ai4 = {0,0,0,0}, ao4 = {0,0,0,0};

        // ---- VGPR-stashed k-pairs (zero memory traffic, hides P latency) --
        FOR_REGP(DOTW)

        // ---- LDS-stashed k-pairs (DS pipe) ----
        #pragma unroll
        for (int j = 0; j < LDSP; ++j) {
            const half2_t hk = *(const half2_t*)&combHh[(k0h + j) * 2];
            float4 rf = wst[sl * LDSP + j][0][lane];
            float4 ri = wst[sl * LDSP + j][1][lane];
            float4 ro = wst[sl * LDSP + j][2][lane];
            const half2_t* wfp = (const half2_t*)&rf;
            const half2_t* wip = (const half2_t*)&ri;
            const half2_t* wop = (const half2_t*)&ro;
            af.x  = FDOT2(wfp[0], hk, af.x);  af.y  = FDOT2(wfp[1], hk, af.y);
            af.z  = FDOT2(wfp[2], hk, af.z);  af.w  = FDOT2(wfp[3], hk, af.w);
            ai4.x = FDOT2(wip[0], hk, ai4.x); ai4.y = FDOT2(wip[1], hk, ai4.y);
            ai4.z = FDOT2(wip[2], hk, ai4.z); ai4.w = FDOT2(wip[3], hk, ai4.w);
            ao4.x = FDOT2(wop[0], hk, ao4.x); ao4.y = FDOT2(wop[1], hk, ao4.y);
            ao4.z = FDOT2(wop[2], hk, ao4.z); ao4.w = FDOT2(wop[3], hk, ao4.w);
        }

        *(float4*)&part[buf][0][sl][cg] = af;
        *(float4*)&part[buf][1][sl][cg] = ai4;
        *(float4*)&part[buf][2][sl][cg] = ao4;
        __syncthreads();   // the ONLY barrier: part[buf] write -> read

        // ---- per-column gate math (thread tid owns column tid) ----
        // combHh is wave-private; part[buf^1] is written next step, and a
        // lagging wave's part[buf] reads are protected by the next step's
        // barrier before anyone re-writes part[buf].
        const int n = tid;
        float fp = pf + part[buf][0][0][n] + part[buf][0][1][n]
                      + part[buf][0][2][n] + part[buf][0][3][n];
        float ip = pi + part[buf][1][0][n] + part[buf][1][1][n]
                      + part[buf][1][2][n] + part[buf][1][3][n];
        float op = po + part[buf][2][0][n] + part[buf][2][1][n]
                      + part[buf][2][2][n] + part[buf][2][3][n];
        const float f = sigmoidf_(fp);
        const float i = sigmoidf_(ip);
        const float z = tanhf_(ip);      // pre_i reused for tanh per reference
        const float o = sigmoidf_(op);
        c     = c * f + z * i;
        h_reg = tanhf_(c) * o;
        combHh[n] = (_Float16)h_reg;                 // wave-private publish
        out[((size_t)b * N + t) * DOUT + n] = h_reg; // raw h; outproj fixes up
    }

    // unreachable at runtime (N==2048): forces the VGPR stash live across
    // the loop so the allocator cannot demote it to per-step reloads.
    if (N == -1) { float s = 0.f; FOR_REGP(KEEPW) out[tid] = s; }

    // finals: d_out = [ outs (B*N*DOUT) | h_final (B*DH) | c_final (B*DC) ]
    float* hf = out + (size_t)B_ * N * DOUT;
    float* cf = hf + (size_t)B_ * DH;
    hf[b * DH + tid] = h_reg;
    cf[b * DC + tid] = c;
}

// ---------------------------------------------------------------------------
// Phase 3: in-place out[m,:] = sigmoid(out[m,:] @ Wout + bout), 32 rows/block.
// ---------------------------------------------------------------------------
__global__ __launch_bounds__(256) void outproj(
    const float* __restrict__ Wout, const float* __restrict__ bout,
    const int* __restrict__ Np, float* __restrict__ out)
{
    const int N = *Np;
    const size_t m0 = (size_t)blockIdx.x * 32;
    if (m0 >= (size_t)B_ * N) return;

    const int tid  = threadIdx.x;
    const int lane = tid & 63;
    const int rg   = tid >> 6;
    const int c4   = lane * 4;

    __shared__ __align__(16) float Hs[32][256];

    #pragma unroll
    for (int j = 0; j < 8; ++j) {
        const int f4 = tid + j * 256;
        const int r  = f4 >> 6;
        const int k4 = (f4 & 63) * 4;
        *(float4*)&Hs[r][k4] = *(const float4*)(out + (m0 + r) * DOUT + k4);
    }
    __syncthreads();

    float4 acc[8];
    const float4 bz = *(const float4*)(bout + c4);
    #pragma unroll
    for (int r = 0; r < 8; ++r) acc[r] = bz;

    #pragma unroll 4
    for (int k = 0; k < 256; ++k) {
        const float4 wv = *(const float4*)(Wout + (size_t)k * DOUT + c4);
        #pragma unroll
        for (int r = 0; r < 8; ++r) {
            const float hv = Hs[rg * 8 + r][k];
            acc[r].x += hv * wv.x; acc[r].y += hv * wv.y;
            acc[r].z += hv * wv.z; acc[r].w += hv * wv.w;
        }
    }
    #pragma unroll
    for (int r = 0; r < 8; ++r) {
        float4 q;
        q.x = sigmoidf_(acc[r].x); q.y = sigmoidf_(acc[r].y);
        q.z = sigmoidf_(acc[r].z); q.w = sigmoidf_(acc[r].w);
        *(float4*)(out + (m0 + rg * 8 + r) * DOUT + c4) = q;
    }
}

// ---------------------------------------------------------------------------
// Fallback: round-0 kernel (proven 28 ms) if workspace is too small.
// ---------------------------------------------------------------------------
__global__ __launch_bounds__(256) void lstm_persistent(
    const float* __restrict__ x,    const float* __restrict__ h0,
    const float* __restrict__ c0,   const float* __restrict__ Wf,
    const float* __restrict__ bf,   const float* __restrict__ Wi,
    const float* __restrict__ bi,   const float* __restrict__ Wo,
    const float* __restrict__ bo,   const float* __restrict__ Wout,
    const float* __restrict__ bout, const int* __restrict__ Np,
    float* __restrict__ out)
{
    const int b   = blockIdx.x;
    const int tid = threadIdx.x;
    const int sl  = tid >> 6;
    const int cg  = (tid & 63) * 4;
    const int N   = *Np;

    __shared__ float comb[K2];
    __shared__ float part[3][4][DC];

    float c     = c0[b * DC + tid];
    float h_reg = h0[b * DH + tid];
    comb[DIN + tid] = h_reg;
    comb[tid]       = x[((size_t)b * T_ + 0) * DIN + tid];
    __syncthreads();

    const size_t xbase = (size_t)b * T_ * DIN;

    for (int t = 0; t < N; ++t) {
        float4 af = {0,0,0,0}, ai = {0,0,0,0}, ao = {0,0,0,0};
        const int k0 = sl * 128;
        #pragma unroll 4
        for (int k = k0; k < k0 + 128; ++k) {
            const float ck = comb[k];
            const float4 wf = *(const float4*)(Wf + (size_t)k * DC + cg);
            const float4 wi = *(const float4*)(Wi + (size_t)k * DC + cg);
            const float4 wo = *(const float4*)(Wo + (size_t)k * DC + cg);
            af.x += ck*wf.x; af.y += ck*wf.y; af.z += ck*wf.z; af.w += ck*wf.w;
            ai.x += ck*wi.x; ai.y += ck*wi.y; ai.z += ck*wi.z; ai.w += ck*wi.w;
            ao.x += ck*wo.x; ao.y += ck*wo.y; ao.z += ck*wo.z; ao.w += ck*wo.w;
        }
        *(float4*)&part[0][sl][cg] = af;
        *(float4*)&part[1][sl][cg] = ai;
        *(float4*)&part[2][sl][cg] = ao;
        __syncthreads();

        const int n = tid;
        float fp = bf[n] + part[0][0][n] + part[0][1][n] + part[0][2][n] + part[0][3][n];
        float ip = bi[n] + part[1][0][n] + part[1][1][n] + part[1][2][n] + part[1][3][n];
        float op = bo[n] + part[2][0][n] + part[2][1][n] + part[2][2][n] + part[2][3][n];
        const float f = sigmoidf_(fp);
        const float i = sigmoidf_(ip);
        const float z = tanhf_(ip);
        const float o = sigmoidf_(op);
        c     = c * f + z * i;
        h_reg = tanhf_(c) * o;
        __syncthreads();

        comb[DIN + n] = h_reg;
        if (t + 1 < N) comb[n] = x[xbase + (size_t)(t + 1) * DIN + n];
        __syncthreads();

        float4 aq = {0,0,0,0};
        const int q0 = sl * 64;
        #pragma unroll 4
        for (int k = q0; k < q0 + 64; ++k) {
            const float hk = comb[DIN + k];
            const float4 w = *(const float4*)(Wout + (size_t)k * DOUT + cg);
            aq.x += hk*w.x; aq.y += hk*w.y; aq.z += hk*w.z; aq.w += hk*w.w;
        }
        *(float4*)&part[0][sl][cg] = aq;
        __syncthreads();
        const float q = bout[n] + part[0][0][n] + part[0][1][n]
                                + part[0][2][n] + part[0][3][n];
        out[((size_t)b * N + t) * DOUT + n] = sigmoidf_(q);
        __syncthreads();
    }

    float* hf = out + (size_t)B_ * N * DOUT;
    float* cf = hf + (size_t)B_ * DH;
    hf[b * DH + tid] = h_reg;
    cf[b * DC + tid] = c;
}

extern "C" void kernel_launch(void* const* d_in, const int* in_sizes, int n_in,
                              void* d_out, int out_size, void* d_ws, size_t ws_size,
                              hipStream_t stream) {
    const float* x    = (const float*)d_in[0];
    const float* h0   = (const float*)d_in[1];
    const float* c0   = (const float*)d_in[2];
    const float* Wf   = (const float*)d_in[3];
    const float* bf   = (const float*)d_in[4];
    const float* Wi   = (const float*)d_in[5];
    const float* bi   = (const float*)d_in[6];
    const float* Wo   = (const float*)d_in[7];
    const float* bo   = (const float*)d_in[8];
    const float* Wout = (const float*)d_in[9];
    const float* bout = (const float*)d_in[10];
    const int*   Np   = (const int*)d_in[11];
    float* out = (float*)d_out;

    const size_t PSIZE  = (size_t)B_ * T_ * 768 * sizeof(float);   // 403 MB
    const size_t WPSIZE = (size_t)3 * 128 * 256 * 4;               // 393 KB
    if (ws_size >= PSIZE + WPSIZE) {
        float*   P  = (float*)d_ws;
        half2_t* Wp = (half2_t*)((char*)d_ws + PSIZE);
        hipLaunchKernelGGL(packw, dim3(3, 16), dim3(256), 0, stream,
                           Wf, Wi, Wo, Wp);
        hipLaunchKernelGGL(xgemm, dim3((B_ * T_) / 32, 3), dim3(256), 0, stream,
                           x, Wf, bf, Wi, bi, Wo, bo, P);
        hipLaunchKernelGGL(lstm_rec6, dim3(B_), dim3(256), 0, stream,
                           P, (const float4*)Wp, h0, c0, Np, out);
        hipLaunchKernelGGL(outproj, dim3((B_ * T_) / 32), dim3(256), 0, stream,
                           Wout, bout, Np, out);
    } else {
        hipLaunchKernelGGL(lstm_persistent, dim3(B_), dim3(256), 0, stream,
                           x, h0, c0, Wf, bf, Wi, bi, Wo, bo, Wout, bout, Np, out);
    }
}